// Round 6
// baseline (189.486 us; speedup 1.0000x reference)
//
#include <hip/hip_runtime.h>
#include <stdint.h>

#define IMG 224
#define OUT_DIM 112
#define NCH 16

typedef __fp16 half2_t __attribute__((ext_vector_type(2)));
typedef __fp16 half8_t __attribute__((ext_vector_type(8)));
typedef float floatx4 __attribute__((ext_vector_type(4)));

// d_ws layout (uint32 words):
//   [0 .. 31]   : 16 x float2 (scale, shift) per channel (folds conv_b, mean, beta)
//   [32 .. 287] : weight table, 16 ch x 16 dwords; dword d=3r+j (r<5): j<2 ->
//                 (w[r*5+2j], w[r*5+2j+1]); j==2 -> (w[r*5+4], 0); d=15 -> 0.
//                 Same layout works for even and odd pixels (odd uses shifted input pairs).
#define WS_WTAB 32

__global__ void prep_kernel(const float* __restrict__ conv_w,
                            const float* __restrict__ conv_b,
                            const float* __restrict__ gamma,
                            const float* __restrict__ beta,
                            const float* __restrict__ run_mean,
                            const float* __restrict__ run_var,
                            uint32_t* __restrict__ ws)
{
    int ch = threadIdx.x;
    if (ch >= NCH) return;
    float s = gamma[ch] * rsqrtf(run_var[ch] + 1e-5f);
    float t = fmaf(s, conv_b[ch] - run_mean[ch], beta[ch]);
    ((float2*)ws)[ch] = make_float2(s, t);

    const float* w = conv_w + ch * 25;
    uint32_t* wt = ws + WS_WTAB + ch * 16;
    for (int d = 0; d < 16; ++d) {
        float v0 = 0.f, v1 = 0.f;
        if (d < 15) {
            int r = d / 3, j = d - 3 * r;
            if (j < 2) { v0 = w[r * 5 + 2 * j]; v1 = w[r * 5 + 2 * j + 1]; }
            else       { v0 = w[r * 5 + 4]; }
        }
        half2_t h = __builtin_amdgcn_cvt_pkrtz(v0, v1);
        wt[d] = __builtin_bit_cast(uint32_t, h);
    }
}

// XOR-swizzled im2col chunk address (layout verified numerically in r5).
__device__ __forceinline__ uint32_t imc_addr(uint32_t P, uint32_t q) {
    return (P >> 1) * 128u + ((((P & 1u) << 2) | q) ^ ((P >> 1) & 7u)) * 16u;
}

__device__ __forceinline__ uint32_t pk(float a, float b) {
    return __builtin_bit_cast(uint32_t, __builtin_amdgcn_cvt_pkrtz(a, b));
}

__global__ __launch_bounds__(256)
void conv_mfma(const float* __restrict__ x,
               const uint32_t* __restrict__ ws,
               float* __restrict__ out)
{
    // 32 KB im2col (512 pixels x 64B) -> 5 blocks/CU, ~20 waves/CU.
    // (r5's 64 KB allowed only 2 blocks/CU -> load-latency-bound at 18% occupancy.)
    __shared__ uint32_t imc[8192];

    const int tid = threadIdx.x;
    const int bx = blockIdx.x, by = blockIdx.y, b = blockIdx.z;
    const float* xb = x + (size_t)b * IMG * IMG;

    // ---------- build phase: 2 horizontally-adjacent conv pixels / thread ----------
    const int px = tid & 15;        // pixel-pair column (conv x = 2px, 2px+1)
    const int cy = tid >> 4;        // conv row within 32x16 tile
    const int gx0 = bx * 32 + 2 * px - 2;   // leftmost input col of 5x6 patch
    const int gy0 = by * 16 + cy - 2;       // topmost input row

    float f[5][6];
    if (bx >= 1 && bx <= 5 && by >= 1 && by <= 12) {
        #pragma unroll
        for (int r = 0; r < 5; ++r) {
            const float* rowp = xb + (gy0 + r) * IMG + gx0;   // gx0 even -> 8B aligned
            #pragma unroll
            for (int j = 0; j < 3; ++j) {
                float2 v = *(const float2*)(rowp + 2 * j);
                f[r][2 * j] = v.x; f[r][2 * j + 1] = v.y;
            }
        }
    } else {
        #pragma unroll
        for (int r = 0; r < 5; ++r) {
            int gy = gy0 + r;
            #pragma unroll
            for (int j = 0; j < 6; ++j) {
                int gx = gx0 + j;
                f[r][j] = ((unsigned)gy < IMG && (unsigned)gx < IMG)
                        ? xb[gy * IMG + gx] : 0.f;
            }
        }
    }

    // even pixel pairs (c0,c1)(c2,c3)(c4,c5); odd (c1,c2)(c3,c4)(c5,c5).
    // weight pairs per row: (w0,w1)(w2,w3)(w4,0) -> last pair's 2nd tap is free.
    uint32_t e[5][3], o[5][3];
    #pragma unroll
    for (int r = 0; r < 5; ++r) {
        e[r][0] = pk(f[r][0], f[r][1]);
        e[r][1] = pk(f[r][2], f[r][3]);
        e[r][2] = pk(f[r][4], f[r][5]);
        o[r][0] = pk(f[r][1], f[r][2]);
        o[r][1] = pk(f[r][3], f[r][4]);
        o[r][2] = pk(f[r][5], f[r][5]);
    }

    const uint32_t Pe = (uint32_t)(cy * 32 + 2 * px);
    {
        uint4 c0 = {e[0][0], e[0][1], e[0][2], e[1][0]};
        uint4 c1 = {e[1][1], e[1][2], e[2][0], e[2][1]};
        uint4 c2 = {e[2][2], e[3][0], e[3][1], e[3][2]};
        uint4 c3 = {e[4][0], e[4][1], e[4][2], 0u};
        *(uint4*)((char*)imc + imc_addr(Pe, 0)) = c0;
        *(uint4*)((char*)imc + imc_addr(Pe, 1)) = c1;
        *(uint4*)((char*)imc + imc_addr(Pe, 2)) = c2;
        *(uint4*)((char*)imc + imc_addr(Pe, 3)) = c3;
    }
    {
        uint4 c0 = {o[0][0], o[0][1], o[0][2], o[1][0]};
        uint4 c1 = {o[1][1], o[1][2], o[2][0], o[2][1]};
        uint4 c2 = {o[2][2], o[3][0], o[3][1], o[3][2]};
        uint4 c3 = {o[4][0], o[4][1], o[4][2], 0u};
        *(uint4*)((char*)imc + imc_addr(Pe + 1, 0)) = c0;
        *(uint4*)((char*)imc + imc_addr(Pe + 1, 1)) = c1;
        *(uint4*)((char*)imc + imc_addr(Pe + 1, 2)) = c2;
        *(uint4*)((char*)imc + imc_addr(Pe + 1, 3)) = c3;
    }

    // per-lane constants (barrier-independent)
    const int lane = tid & 63;
    const int n = lane & 15;          // channel (B/D) AND pixel row index m (A)
    const int q = lane >> 4;          // k-chunk (A/B) AND output x-group (D)
    uint4 bw = ((const uint4*)(ws + WS_WTAB))[n * 4 + q];
    half8_t bfrag = __builtin_bit_cast(half8_t, bw);
    float2 st = ((const float2*)ws)[n];

    __syncthreads();

    // ---------- MFMA phase: 4 pooled-row/x-half slots per wave ----------
    const int w = tid >> 6;
    float* outb = out + (size_t)b * NCH * (OUT_DIM * OUT_DIM)
                      + (size_t)n * (OUT_DIM * OUT_DIM);

    #pragma unroll
    for (int i = 0; i < 4; ++i) {
        const int gp = w * 4 + i;
        const int Y = gp >> 1, xh = gp & 1;                    // pooled row, x-half
        const uint32_t P0 = 64u * Y + 16u * xh + (uint32_t)n;  // conv row 2Y
        uint4 a0w = *(const uint4*)((const char*)imc + imc_addr(P0, q));
        uint4 a1w = *(const uint4*)((const char*)imc + imc_addr(P0 + 32u, q));
        floatx4 z = {0.f, 0.f, 0.f, 0.f};
        floatx4 d0 = __builtin_amdgcn_mfma_f32_16x16x32_f16(
            __builtin_bit_cast(half8_t, a0w), bfrag, z, 0, 0, 0);
        floatx4 d1 = __builtin_amdgcn_mfma_f32_16x16x32_f16(
            __builtin_bit_cast(half8_t, a1w), bfrag, z, 0, 0, 0);
        // y-pool across the two row-MFMAs, x-pool across reg pairs (intra-lane)
        float c0 = fmaxf(d0[0], d1[0]);
        float c1 = fmaxf(d0[1], d1[1]);
        float c2 = fmaxf(d0[2], d1[2]);
        float c3 = fmaxf(d0[3], d1[3]);
        float o0 = fmaxf(fmaf(fmaxf(c0, c1), st.x, st.y), 0.f);
        float o1 = fmaxf(fmaf(fmaxf(c2, c3), st.x, st.y), 0.f);
        const int gyp = by * 8 + Y;
        const int gxp = bx * 16 + xh * 8 + 2 * q;
        *(float2*)(outb + gyp * OUT_DIM + gxp) = make_float2(o0, o1);
    }
}

extern "C" void kernel_launch(void* const* d_in, const int* in_sizes, int n_in,
                              void* d_out, int out_size, void* d_ws, size_t ws_size,
                              hipStream_t stream) {
    const float* x        = (const float*)d_in[0];
    const float* conv_w   = (const float*)d_in[1];
    const float* conv_b   = (const float*)d_in[2];
    const float* gamma    = (const float*)d_in[3];
    const float* beta     = (const float*)d_in[4];
    const float* run_mean = (const float*)d_in[5];
    const float* run_var  = (const float*)d_in[6];
    float* out = (float*)d_out;
    uint32_t* ws = (uint32_t*)d_ws;

    prep_kernel<<<1, 64, 0, stream>>>(conv_w, conv_b, gamma, beta, run_mean, run_var, ws);

    dim3 grid(7, 14, 128);   // 32x16 conv tile -> 16x8 pooled
    dim3 block(256);
    conv_mfma<<<grid, block, 0, stream>>>(x, ws, out);
}